// Round 8
// baseline (84.191 us; speedup 1.0000x reference)
//
#include <hip/hip_runtime.h>
#include <hip/hip_bf16.h>
#include <math.h>

#define BS 4096
#define DD 512
#define NCLS 100
#define NROWS 8192
#define NSLAB 512            // 512 slabs x 16 cols
#define INV_T (1.0f / 0.07f)

typedef __attribute__((ext_vector_type(8))) short short8;      // 8 bf16 (4 VGPR)
typedef __attribute__((ext_vector_type(8))) unsigned short ushort8;
typedef __attribute__((ext_vector_type(4))) float f32x4;

__device__ __forceinline__ unsigned short f2bf(float x) {
    __hip_bfloat16 h = __float2bfloat16(x);
    return *reinterpret_cast<unsigned short*>(&h);
}

// ---- K0: protos fp32 -> bf16 once (112 rows, zero-padded); zero out ----
__global__ __launch_bounds__(256) void k_prep(const float* __restrict__ protos,
                                              unsigned short* __restrict__ pB,
                                              float* __restrict__ out) {
    const int bid = blockIdx.x, tid = threadIdx.x;
    if (bid < 28) {                          // 112*512/8 = 7168 8-elem chunks
        const int t = bid * 256 + tid;
        const int r = t >> 6;
        const int kk = (t & 63) << 3;
        float4 f0 = {0,0,0,0}, f1 = {0,0,0,0};
        if (r < NCLS) {
            const float4* s = (const float4*)(protos + (size_t)r * DD + kk);
            f0 = s[0]; f1 = s[1];
        }
        ushort8 o;
        o[0]=f2bf(f0.x); o[1]=f2bf(f0.y); o[2]=f2bf(f0.z); o[3]=f2bf(f0.w);
        o[4]=f2bf(f1.x); o[5]=f2bf(f1.y); o[6]=f2bf(f1.z); o[7]=f2bf(f1.w);
        *reinterpret_cast<ushort8*>(pB + (size_t)r * DD + kk) = o;
    } else if (tid == 0) {
        out[0] = 0.f;
    }
}

// ---- K1: GEMM (128x16 logits per block, in regs) + per-(class,slab) stats + stash ----
// Block nt owns contrast columns [nt*16, nt*16+16). 8 waves; wave w -> M-rows [w*16,w*16+16)
// (rows 100..127 are clamped duplicates of row 99, never published).
__global__ __launch_bounds__(512) void k_gemm(const float* __restrict__ feats,
                                              const unsigned short* __restrict__ pB,
                                              const int* __restrict__ labels,
                                              float4* __restrict__ PA,   // [NCLS][NSLAB] {m1,m2,ea,ee}
                                              float4* __restrict__ PBd,  // [NCLS][NSLAB] {pp,nn,i1,0}
                                              float* __restrict__ stash) // [NROWS] matched logit per col
{
    __shared__ char lds[16 * DD * 2];        // 16 KB bf16 [16][512], byte ^= (row&7)<<4
    const int nt = blockIdx.x, tid = threadIdx.x;
    const int v  = nt >> 8;
    const int b0 = (nt & 255) * 16;

    // issue ALL 4 feature loads -> regs (one HBM latency), then convert + swizzled LDS write
    float4 fr[4];
#pragma unroll
    for (int it = 0; it < 4; ++it) {
        const int i = tid + it * 512;        // 2048 float4 chunks, coalesced per 128-thread row
        const int r = i >> 7, c4 = i & 127;
        fr[it] = *(const float4*)(feats + (size_t)((b0 + r) * 2 + v) * DD + c4 * 4);
    }
#pragma unroll
    for (int it = 0; it < 4; ++it) {
        const int i = tid + it * 512;
        const int r = i >> 7, c4 = i & 127;
        ushort4 o = { f2bf(fr[it].x), f2bf(fr[it].y), f2bf(fr[it].z), f2bf(fr[it].w) };
        const int byte = (r * 1024 + c4 * 8) ^ ((r & 7) << 4);
        *reinterpret_cast<ushort4*>(&lds[byte]) = o;
    }
    __syncthreads();

    const int w = tid >> 6, lane = tid & 63;
    const int m = lane & 15, kb = lane >> 4;
    const int arow = min(w * 16 + m, NCLS - 1);            // clamp; rows >=100 never published
    const short8* apv = (const short8*)((const short*)pB + (size_t)arow * DD + kb * 8);

    const int swz  = (m & 7) << 4;
    const int base = m * 1024 + kb * 16;
    f32x4 acc = {};
#pragma unroll
    for (int k = 0; k < 16; ++k) {           // K = 512 = 16 x 32; A: one 16B L2-warm load
        const short8 a = apv[k * 4];
        const short8 b = *reinterpret_cast<const short8*>(&lds[(base + k * 64) ^ swz]);
        acc = __builtin_amdgcn_mfma_f32_16x16x32_bf16(a, b, acc, 0, 0, 0);
    }
#pragma unroll
    for (int r = 0; r < 4; ++r) acc[r] *= INV_T;

    // C/D layout: col = lane&15, row = w*16 + kb*4 + r
    const int j0  = nt * 16 + m;
    const int lb0 = labels[j0 & (BS - 1)];

    // stash: column j0's matched logit is S[lb0][j0] — exactly one lane holds it (lb0<100 -> w<=6)
    if ((lb0 >> 4) == w && ((lb0 >> 2) & 3) == kb) {
        const int rr = lb0 & 3;
        stash[j0] = (rr==0)?acc[0]:(rr==1)?acc[1]:(rr==2)?acc[2]:acc[3];
    }

    // per-class-row stats over this slab's 16 columns: 16-lane shfl butterflies (4 indep chains)
#pragma unroll
    for (int r = 0; r < 4; ++r) {
        const int row = w * 16 + kb * 4 + r;
        const float x0 = acc[r];
        float m1 = x0, m2 = -INFINITY; int i1 = j0;
#pragma unroll
        for (int s = 1; s < 16; s <<= 1) {   // disjoint-union butterfly: exact top-2
            const float om1 = __shfl_xor(m1, s);
            const float om2 = __shfl_xor(m2, s);
            const int   oi1 = __shfl_xor(i1, s);
            if (om1 > m1) { m2 = fmaxf(m1, om2); m1 = om1; i1 = oi1; }
            else          { m2 = fmaxf(m2, om1); }
        }
        float ea = __expf(x0 - m1);
        float ee = (j0 != i1) ? __expf(x0 - m2) : 0.f;
        float pp = (lb0 == row) ? x0 - m1 : 0.f;
        float nn = (lb0 == row) ? 1.f : 0.f;
#pragma unroll
        for (int s = 1; s < 16; s <<= 1) {
            ea += __shfl_xor(ea, s);
            ee += __shfl_xor(ee, s);
            pp += __shfl_xor(pp, s);
            nn += __shfl_xor(nn, s);
        }
        if (m == 0 && row < NCLS) {          // plain stores; next kernel sees them
            PA[row * NSLAB + nt]  = make_float4(m1, m2, ea, ee);
            PBd[row * NSLAB + nt] = make_float4(pp, nn, (float)i1, 0.f);
        }
    }
}

// ---- K2: per-class merge of 512 slab partials + loss ----
__global__ __launch_bounds__(512) void k_merge(const float4* __restrict__ PA,
                                               const float4* __restrict__ PBd,
                                               const float* __restrict__ stash,
                                               const int* __restrict__ labels,
                                               float* __restrict__ out) {
    const int c = blockIdx.x, tid = threadIdx.x;
    const float4 A  = PA[c * NSLAB + tid];
    const float4 Bq = PBd[c * NSLAB + tid];
    const float m1 = A.x, m2 = A.y, ea = A.z, ee = A.w;
    const float pp = Bq.x, nn = Bq.y;
    const int   i1 = (int)Bq.z;

    __shared__ float s1[512], s2[512];
    __shared__ int   si[512];
    s1[tid] = m1; s2[tid] = m2; si[tid] = i1;
    __syncthreads();
    for (int s = 256; s > 0; s >>= 1) {
        if (tid < s) {
            const float b1 = s1[tid + s], b2 = s2[tid + s];
            if (b1 > s1[tid]) { s2[tid] = fmaxf(s1[tid], b2); s1[tid] = b1; si[tid] = si[tid + s]; }
            else              { s2[tid] = fmaxf(s2[tid], b1); }
        }
        __syncthreads();
    }
    const float gm1 = s1[0], gm2 = s2[0];
    const int   gi1 = si[0];
    __syncthreads();

    // rescaled contributions (all exponents <= 0)
    const float e1c = ea * __expf(m1 - gm1);
    const float e2c = ((gi1 >> 4) == tid) ? ee * __expf(m2 - gm2)
                                          : ea * __expf(m1 - gm2);
    const float pc  = pp + nn * (m1 - gm1);
    __shared__ float r1[512], r2[512], r3[512];
    r1[tid] = e1c; r2[tid] = e2c; r3[tid] = pc;
    __syncthreads();
    for (int s = 256; s > 0; s >>= 1) {
        if (tid < s) { r1[tid] += r1[tid + s]; r2[tid] += r2[tid + s]; r3[tid] += r3[tid + s]; }
        __syncthreads();
    }
    const float E1 = r1[0], E2 = r2[0], Pg = r3[0];
    __syncthreads();

    // loss over matched columns (label[j]==c); stash[j] = S[c][j]
    float ls = 0.f;
    const float tmax = (gm2 - gm1) + __logf(E2);             // cancellation-free argmax row
    for (int it = 0; it < 4; ++it) {
        const int j = it * 2048 + tid * 4;
        const int4   lv = *(const int4*)(labels + (j & (BS - 1)));
        const float4 sv = *(const float4*)(stash + j);
        if (lv.x == c) ls += (j + 0 == gi1) ? tmax : __logf(E1 - __expf(sv.x - gm1));
        if (lv.y == c) ls += (j + 1 == gi1) ? tmax : __logf(E1 - __expf(sv.y - gm1));
        if (lv.z == c) ls += (j + 2 == gi1) ? tmax : __logf(E1 - __expf(sv.z - gm1));
        if (lv.w == c) ls += (j + 3 == gi1) ? tmax : __logf(E1 - __expf(sv.w - gm1));
    }
    s1[tid] = ls;
    __syncthreads();
    for (int s = 256; s > 0; s >>= 1) {
        if (tid < s) s1[tid] += s1[tid + s];
        __syncthreads();
    }
    if (tid == 0) atomicAdd(out, (s1[0] - Pg) / (float)NROWS);
}

// ==========================================================================
extern "C" void kernel_launch(void* const* d_in, const int* in_sizes, int n_in,
                              void* d_out, int out_size, void* d_ws, size_t ws_size,
                              hipStream_t stream) {
    const float* feats  = (const float*)d_in[0];
    const int*   labels = (const int*)d_in[1];
    const float* protos = (const float*)d_in[2];
    float* out = (float*)d_out;

    char* w = (char*)d_ws;
    size_t off = 0;
    auto take = [&](size_t n) { size_t o = off; off += (n + 255) & ~(size_t)255; return o; };
    unsigned short* pB    = (unsigned short*)(w + take((size_t)112 * DD * 2));
    float4*         PA    = (float4*)(w + take((size_t)NCLS * NSLAB * 16));
    float4*         PBd   = (float4*)(w + take((size_t)NCLS * NSLAB * 16));
    float*          stash = (float*)(w + take((size_t)NROWS * 4));

    k_prep<<<29, 256, 0, stream>>>(protos, pB, out);
    k_gemm<<<NSLAB, 512, 0, stream>>>(feats, pB, labels, PA, PBd, stash);
    k_merge<<<NCLS, 512, 0, stream>>>(PA, PBd, stash, labels, out);
}